// Round 11
// baseline (367.925 us; speedup 1.0000x reference)
//
#include <hip/hip_runtime.h>
#include <hip/hip_bf16.h>

typedef __bf16 bf16;
typedef __bf16 bf16x8 __attribute__((ext_vector_type(8)));
typedef __bf16 bf16x4 __attribute__((ext_vector_type(4)));
typedef float f32x4 __attribute__((ext_vector_type(4)));
typedef unsigned int uint4v __attribute__((ext_vector_type(4)));
typedef unsigned int uint2v __attribute__((ext_vector_type(2)));

#define LOG2E 1.44269504088896340736f

typedef __attribute__((address_space(1))) const unsigned int guint;
typedef __attribute__((address_space(3))) unsigned int luint;

__device__ __forceinline__ void gload_lds16(const bf16* g, bf16* l) {
  // async global->LDS, 16B per lane; LDS dest = wave-uniform base + lane*16
  __builtin_amdgcn_global_load_lds((guint*)g, (luint*)l, 16, 0, 0);
}

// ------- K1: fused transpose x[b][i][n] (f32) -> xt[b][n][i] (bf16) for q,k,v ---------
__global__ __launch_bounds__(256) void k_transpose3(const float* __restrict__ q,
                                                    const float* __restrict__ k,
                                                    const float* __restrict__ v,
                                                    bf16* __restrict__ tq,
                                                    bf16* __restrict__ tk,
                                                    bf16* __restrict__ tv) {
  __shared__ bf16 T[64][72];
  const int t = threadIdx.x;
  const int n0 = blockIdx.x * 64;
  const int i0 = blockIdx.y * 64;
  const int z = blockIdx.z;
  const int b = z & 3, which = z >> 2;
  const float* src = (which == 0) ? q : ((which == 1) ? k : v);
  bf16* dst = (which == 0) ? tq : ((which == 1) ? tk : tv);
  const size_t srcb = (size_t)b * 1024 * 2048;
#pragma unroll
  for (int p = 0; p < 2; ++p) {
    int idx = p * 256 + t;
    int row = idx >> 3;   // i-local
    int seg = idx & 7;    // 8 n elems
    const float* sp = src + srcb + (size_t)(i0 + row) * 2048 + n0 + seg * 8;
    f32x4 a = *(const f32x4*)sp;
    f32x4 c = *(const f32x4*)(sp + 4);
    bf16x8 o;
#pragma unroll
    for (int e = 0; e < 4; ++e) { o[e] = (bf16)a[e]; o[4 + e] = (bf16)c[e]; }
    *(bf16x8*)&T[row][seg * 8] = o;
  }
  __syncthreads();
  const int j = t >> 2;       // n-local
  const int iseg = t & 3;     // 16 i elems
  bf16x8 o0, o1;
#pragma unroll
  for (int e = 0; e < 8; ++e) o0[e] = T[iseg * 16 + e][j];
#pragma unroll
  for (int e = 0; e < 8; ++e) o1[e] = T[iseg * 16 + 8 + e][j];
  bf16* dp = dst + (size_t)b * 2048 * 1024 + (size_t)(n0 + j) * 1024 + i0 + iseg * 16;
  *(bf16x8*)dp = o0;
  *(bf16x8*)(dp + 8) = o1;
}

// ------- K2a: fused QKV GEMM, 8-phase 256x256 deep-pipelined schedule ------------------
// Geometry (m201 template): 512 threads, 8 waves (2M x 4N), per-wave 128x64 out,
// BK=64, LDS 128KB = 2 dbuf x (A 256x64 + B 256x64) bf16. Both-sides XOR swizzle
// (round-7 verified). Per K-tile: 4 phases, each {2 gload_lds for tile t+1 ||
// 0-12 ds_read_b128 || s_barrier || setprio(1) 16 MFMA setprio(0) || s_barrier}.
// Tile boundary: vmcnt(0) AFTER 4 phases of compute cover (issue-early/wait-late),
// then barrier; buffer flip by static unroll-by-2 (no runtime LDS bases).
#define G3_BAR() do { __builtin_amdgcn_s_barrier(); __builtin_amdgcn_sched_barrier(0); \
                      asm volatile("" ::: "memory"); } while (0)

#define G3_TILE(AC, BC, AN, BN, KN) do {                                                   \
    bf16x8 bA[4][2], bB[4][2];                                                             \
    /* ---- phase 0: stage pass0; read A(mt0-3) + B(ct0-1); MFMA q00 ---- */               \
    gload_lds16(Ag0 + (KN), (AN) + (size_t)(0 * 512 + w * 64) * 8);                        \
    gload_lds16(Bg0 + (KN), (BN) + (size_t)(0 * 512 + w * 64) * 8);                        \
    _Pragma("unroll") for (int i = 0; i < 4; ++i)                                          \
      _Pragma("unroll") for (int kk = 0; kk < 2; ++kk)                                     \
        bA[i][kk] = *(const bf16x8*)&(AC)[(wr + i * 16 + li) * 64 + ((kk * 4 + q) ^ swz) * 8]; \
    _Pragma("unroll") for (int c = 0; c < 2; ++c)                                          \
      _Pragma("unroll") for (int kk = 0; kk < 2; ++kk)                                     \
        bB[c][kk] = *(const bf16x8*)&(BC)[(wc + c * 16 + li) * 64 + ((kk * 4 + q) ^ swz) * 8]; \
    G3_BAR();                                                                              \
    __builtin_amdgcn_s_setprio(1);                                                         \
    _Pragma("unroll") for (int i = 0; i < 4; ++i)                                          \
      _Pragma("unroll") for (int c = 0; c < 2; ++c)                                        \
        _Pragma("unroll") for (int kk = 0; kk < 2; ++kk)                                   \
          acc[i][c] = __builtin_amdgcn_mfma_f32_16x16x32_bf16(bA[i][kk], bB[c][kk], acc[i][c], 0, 0, 0); \
    __builtin_amdgcn_s_setprio(0);                                                         \
    G3_BAR();                                                                              \
    /* ---- phase 1: stage pass1; read B(ct2-3); MFMA q01 ---- */                          \
    gload_lds16(Ag1 + (KN), (AN) + (size_t)(1 * 512 + w * 64) * 8);                        \
    gload_lds16(Bg1 + (KN), (BN) + (size_t)(1 * 512 + w * 64) * 8);                        \
    _Pragma("unroll") for (int c = 0; c < 2; ++c)                                          \
      _Pragma("unroll") for (int kk = 0; kk < 2; ++kk)                                     \
        bB[2 + c][kk] = *(const bf16x8*)&(BC)[(wc + (2 + c) * 16 + li) * 64 + ((kk * 4 + q) ^ swz) * 8]; \
    G3_BAR();                                                                              \
    __builtin_amdgcn_s_setprio(1);                                                         \
    _Pragma("unroll") for (int i = 0; i < 4; ++i)                                          \
      _Pragma("unroll") for (int c = 0; c < 2; ++c)                                        \
        _Pragma("unroll") for (int kk = 0; kk < 2; ++kk)                                   \
          acc[i][2 + c] = __builtin_amdgcn_mfma_f32_16x16x32_bf16(bA[i][kk], bB[2 + c][kk], acc[i][2 + c], 0, 0, 0); \
    __builtin_amdgcn_s_setprio(0);                                                         \
    G3_BAR();                                                                              \
    /* ---- phase 2: stage pass2; read A(mt4-7); MFMA q11 ---- */                          \
    gload_lds16(Ag2 + (KN), (AN) + (size_t)(2 * 512 + w * 64) * 8);                        \
    gload_lds16(Bg2 + (KN), (BN) + (size_t)(2 * 512 + w * 64) * 8);                        \
    _Pragma("unroll") for (int i = 0; i < 4; ++i)                                          \
      _Pragma("unroll") for (int kk = 0; kk < 2; ++kk)                                     \
        bA[i][kk] = *(const bf16x8*)&(AC)[(wr + (4 + i) * 16 + li) * 64 + ((kk * 4 + q) ^ swz) * 8]; \
    G3_BAR();                                                                              \
    __builtin_amdgcn_s_setprio(1);                                                         \
    _Pragma("unroll") for (int i = 0; i < 4; ++i)                                          \
      _Pragma("unroll") for (int c = 0; c < 2; ++c)                                        \
        _Pragma("unroll") for (int kk = 0; kk < 2; ++kk)                                   \
          acc[4 + i][2 + c] = __builtin_amdgcn_mfma_f32_16x16x32_bf16(bA[i][kk], bB[2 + c][kk], acc[4 + i][2 + c], 0, 0, 0); \
    __builtin_amdgcn_s_setprio(0);                                                         \
    G3_BAR();                                                                              \
    /* ---- phase 3: stage pass3; MFMA q10 (frags live); boundary vmcnt+barrier ---- */    \
    gload_lds16(Ag3 + (KN), (AN) + (size_t)(3 * 512 + w * 64) * 8);                        \
    gload_lds16(Bg3 + (KN), (BN) + (size_t)(3 * 512 + w * 64) * 8);                        \
    G3_BAR();                                                                              \
    __builtin_amdgcn_s_setprio(1);                                                         \
    _Pragma("unroll") for (int i = 0; i < 4; ++i)                                          \
      _Pragma("unroll") for (int c = 0; c < 2; ++c)                                        \
        _Pragma("unroll") for (int kk = 0; kk < 2; ++kk)                                   \
          acc[4 + i][c] = __builtin_amdgcn_mfma_f32_16x16x32_bf16(bA[i][kk], bB[c][kk], acc[4 + i][c], 0, 0, 0); \
    __builtin_amdgcn_s_setprio(0);                                                         \
    asm volatile("s_waitcnt vmcnt(0)" ::: "memory");                                       \
    __builtin_amdgcn_sched_barrier(0);                                                     \
    __builtin_amdgcn_s_barrier();                                                          \
    __builtin_amdgcn_sched_barrier(0);                                                     \
    asm volatile("" ::: "memory");                                                         \
  } while (0)

__global__ __launch_bounds__(512, 2) void k_gemm3(const bf16* __restrict__ Wqb,
                                                  const bf16* __restrict__ Wkb,
                                                  const bf16* __restrict__ Wvb,
                                                  const float* __restrict__ bq,
                                                  const float* __restrict__ bk,
                                                  const float* __restrict__ bv,
                                                  const bf16* __restrict__ tq,
                                                  const bf16* __restrict__ tk,
                                                  const bf16* __restrict__ tv,
                                                  bf16* __restrict__ qp,
                                                  bf16* __restrict__ kp,
                                                  bf16* __restrict__ vp) {
  const int K = 1024, Nn = 2048;
  const int z = blockIdx.z;
  const int b = z & 3, which = z >> 2;
  const bf16* A = (which == 0) ? Wqb : ((which == 1) ? Wkb : Wvb);
  const bf16* Bt = (which == 0) ? tq : ((which == 1) ? tk : tv);
  const float* bias = (which == 0) ? bq : ((which == 1) ? bk : bv);
  bf16* C = (which == 0) ? qp : ((which == 1) ? kp : vp);

  __shared__ bf16 As0[256 * 64], Bs0[256 * 64];   // 32 KB each
  __shared__ bf16 As1[256 * 64], Bs1[256 * 64];   // total 128 KB
  const int t = threadIdx.x;
  const int w = t >> 6, l = t & 63, q = l >> 4, li = l & 15;
  const int o0 = blockIdx.y * 256, n0 = blockIdx.x * 256;
  const bf16* Ab = A + (size_t)o0 * K;
  const bf16* Bb = Bt + (size_t)b * Nn * K + (size_t)n0 * K;
  const int wr = (w >> 2) * 128, wc = (w & 3) * 64;
  f32x4 acc[8][4];
#pragma unroll
  for (int i = 0; i < 8; ++i)
#pragma unroll
    for (int j = 0; j < 4; ++j) acc[i][j] = (f32x4){0.f, 0.f, 0.f, 0.f};

  // staging map: 2048 chunks of 16B per 256x64 tile; pass p stages chunks [p*512, p*512+512)
  int srow_[4], sseg_[4];
#pragma unroll
  for (int p = 0; p < 4; ++p) {
    int ci = p * 512 + t;
    srow_[p] = ci >> 3;
    sseg_[p] = ((ci & 7) ^ (srow_[p] & 7)) * 8;  // pre-swizzled source column
  }
  const bf16* Ag0 = Ab + (size_t)srow_[0] * K + sseg_[0];
  const bf16* Ag1 = Ab + (size_t)srow_[1] * K + sseg_[1];
  const bf16* Ag2 = Ab + (size_t)srow_[2] * K + sseg_[2];
  const bf16* Ag3 = Ab + (size_t)srow_[3] * K + sseg_[3];
  const bf16* Bg0 = Bb + (size_t)srow_[0] * K + sseg_[0];
  const bf16* Bg1 = Bb + (size_t)srow_[1] * K + sseg_[1];
  const bf16* Bg2 = Bb + (size_t)srow_[2] * K + sseg_[2];
  const bf16* Bg3 = Bb + (size_t)srow_[3] * K + sseg_[3];
  const int swz = li & 7;  // read-side swizzle

  // prologue: stage tile k=0 into buf0, drain, publish
  gload_lds16(Ag0, As0 + (size_t)(0 * 512 + w * 64) * 8);
  gload_lds16(Bg0, Bs0 + (size_t)(0 * 512 + w * 64) * 8);
  gload_lds16(Ag1, As0 + (size_t)(1 * 512 + w * 64) * 8);
  gload_lds16(Bg1, Bs0 + (size_t)(1 * 512 + w * 64) * 8);
  gload_lds16(Ag2, As0 + (size_t)(2 * 512 + w * 64) * 8);
  gload_lds16(Bg2, Bs0 + (size_t)(2 * 512 + w * 64) * 8);
  gload_lds16(Ag3, As0 + (size_t)(3 * 512 + w * 64) * 8);
  gload_lds16(Bg3, Bs0 + (size_t)(3 * 512 + w * 64) * 8);
  asm volatile("s_waitcnt vmcnt(0)" ::: "memory");
  __builtin_amdgcn_s_barrier();
  __builtin_amdgcn_sched_barrier(0);
  asm volatile("" ::: "memory");

#pragma unroll 1
  for (int k0 = 0; k0 < K; k0 += 128) {
    const int k1 = k0 + 64;
    const int k2 = (k0 + 128 < K) ? (k0 + 128) : 0;  // final prefetch redundant (clamped)
    G3_TILE(As0, Bs0, As1, Bs1, k1);   // compute tile k0 from buf0; stage k1 -> buf1
    G3_TILE(As1, Bs1, As0, Bs0, k2);   // compute tile k1 from buf1; stage k2 -> buf0
  }

  bf16* Cb = C + (size_t)b * K * Nn;
#pragma unroll
  for (int mt = 0; mt < 8; ++mt) {
#pragma unroll
    for (int r = 0; r < 4; ++r) {
      int o = o0 + wr + mt * 16 + q * 4 + r;
      float bvv = bias[o];
#pragma unroll
      for (int c = 0; c < 4; ++c) {
        int n = n0 + wc + c * 16 + li;
        Cb[(size_t)o * Nn + n] = (bf16)(acc[mt][c][r] + bvv);
      }
    }
  }
}

// ------- K2b: single GEMM (final projection), OT = float. BK=64 + swizzle (round 7). ---
template <typename OT>
__global__ __launch_bounds__(256) void k_gemm(const bf16* __restrict__ A,
                                              const bf16* __restrict__ Bt,
                                              const float* __restrict__ bias,
                                              OT* __restrict__ C,
                                              int M, int K, int Nn) {
  __shared__ bf16 As[128 * 64];
  __shared__ bf16 Bs[128 * 64];
  const int t = threadIdx.x;
  const int w = t >> 6, l = t & 63, q = l >> 4, li = l & 15;
  const int o0 = blockIdx.y * 128, n0 = blockIdx.x * 128;
  const int b = blockIdx.z;
  const bf16* Ab = A + (size_t)o0 * K;
  const bf16* Bb = Bt + (size_t)b * Nn * K + (size_t)n0 * K;
  const int wr = (w >> 1) * 64, wc = (w & 1) * 64;
  f32x4 acc[4][4];
#pragma unroll
  for (int i = 0; i < 4; ++i)
#pragma unroll
    for (int j = 0; j < 4; ++j) acc[i][j] = (f32x4){0.f, 0.f, 0.f, 0.f};

  int srow[4], sseg[4];
#pragma unroll
  for (int p = 0; p < 4; ++p) {
    int ci = p * 256 + t;
    srow[p] = ci >> 3;
    sseg[p] = ((ci & 7) ^ (srow[p] & 7)) * 8;
  }
  const int swz = li & 7;

  for (int k0 = 0; k0 < K; k0 += 64) {
    __syncthreads();
#pragma unroll
    for (int p = 0; p < 4; ++p) {
      gload_lds16(Ab + (size_t)srow[p] * K + k0 + sseg[p], As + (size_t)(p * 256 + w * 64) * 8);
      gload_lds16(Bb + (size_t)srow[p] * K + k0 + sseg[p], Bs + (size_t)(p * 256 + w * 64) * 8);
    }
    __syncthreads();
#pragma unroll
    for (int kk = 0; kk < 2; ++kk) {
      const int cc = ((kk * 4 + q) ^ swz) * 8;
      bf16x8 af[4], bfr[4];
#pragma unroll
      for (int mt = 0; mt < 4; ++mt) af[mt] = *(const bf16x8*)&As[(wr + mt * 16 + li) * 64 + cc];
#pragma unroll
      for (int c = 0; c < 4; ++c) bfr[c] = *(const bf16x8*)&Bs[(wc + c * 16 + li) * 64 + cc];
#pragma unroll
      for (int mt = 0; mt < 4; ++mt)
#pragma unroll
        for (int c = 0; c < 4; ++c)
          acc[mt][c] = __builtin_amdgcn_mfma_f32_16x16x32_bf16(af[mt], bfr[c], acc[mt][c], 0, 0, 0);
    }
  }

  OT* Cb = C + (size_t)b * M * Nn;
#pragma unroll
  for (int mt = 0; mt < 4; ++mt) {
#pragma unroll
    for (int r = 0; r < 4; ++r) {
      int o = o0 + wr + mt * 16 + q * 4 + r;
      float bv = bias[o];
#pragma unroll
      for (int c = 0; c < 4; ++c) {
        int n = n0 + wc + c * 16 + li;
        Cb[(size_t)o * Nn + n] = (OT)(acc[mt][c][r] + bv);
      }
    }
  }
}

// ------- K3: fused RoPE q&k: p[b][hd*16+h][n] -> a[b][h][n][hd], z = which*4+b ---------
__global__ __launch_bounds__(256) void k_rope2(const bf16* __restrict__ qp,
                                               const bf16* __restrict__ kp,
                                               const float* __restrict__ enc,
                                               bf16* __restrict__ qa,
                                               bf16* __restrict__ ka) {
  __shared__ bf16 T[64][72];
  const int t = threadIdx.x;
  const int n0 = blockIdx.x * 64;
  const int h = blockIdx.y;
  const int z = blockIdx.z;
  const int b = z & 3, which = z >> 2;
  const bf16* src = which ? kp : qp;
  bf16* dst = which ? ka : qa;
  const float oscale = which ? 1.0f : 0.125f * LOG2E;
#pragma unroll
  for (int p = 0; p < 2; ++p) {
    int idx = p * 256 + t;
    int hd = idx >> 3;   // hd-local (row d = hd*16+h)
    int seg = idx & 7;
    *(bf16x8*)&T[hd][seg * 8] =
        *(const bf16x8*)(src + (size_t)(b * 1024 + hd * 16 + h) * 2048 + n0 + seg * 8);
  }
  __syncthreads();
  const int j = t >> 2;          // n-local
  const int hd0 = (t & 3) * 16;  // 16 hd elems
  const int n = n0 + j;
  const float* e0 = enc + (size_t)n * 64 + hd0;
  const float* e1 = enc + (size_t)2048 * 64 + (size_t)n * 64 + hd0;
  bf16x8 o0, o1;
#pragma unroll
  for (int i = 0; i < 8; ++i) {
    int e = 2 * i;
    float t0 = (float)T[hd0 + e][j];
    float t1 = (float)T[hd0 + e + 1][j];
    float f00 = e0[e], f01 = e0[e + 1];
    float f10 = e1[e], f11 = e1[e + 1];
    float r0 = (t0 * f00 - t1 * f10) * oscale;
    float r1 = (t1 * f01 + t0 * f11) * oscale;
    if (i < 4) { o0[e & 7] = (bf16)r0; o0[(e & 7) + 1] = (bf16)r1; }
    else       { o1[e & 7] = (bf16)r0; o1[(e & 7) + 1] = (bf16)r1; }
  }
  bf16* dp = dst + ((size_t)(b * 16 + h) * 2048 + n) * 64 + hd0;
  *(bf16x8*)dp = o0;
  *(bf16x8*)(dp + 8) = o1;
}

// ---------------- K4: flash attention v9 (round-9/10 verified version) ------------------
__global__ __launch_bounds__(512, 4) void k_attn(const bf16* __restrict__ qa,
                                                 const bf16* __restrict__ ka,
                                                 const bf16* __restrict__ vp,
                                                 bf16* __restrict__ xo) {
  __shared__ bf16 Ks[64 * 72];     // [m][hd]
  __shared__ bf16 Vs[64 * 72];     // [hd][m]
  const int t = threadIdx.x;
  const int w = t >> 6, l = t & 63, q = l >> 4, li = l & 15;
  const int n0 = blockIdx.x * 256, h = blockIdx.y, b = blockIdx.z;
  const bool oddrow = ((t >> 4) & 1) != 0;  // 16-lane row parity within the wave
  const bf16* Qb = qa + (size_t)(b * 16 + h) * 2048 * 64;
  const bf16* Kb = ka + (size_t)(b * 16 + h) * 2048 * 64;
  const bf16* Vb = vp + (size_t)b * 1024 * 2048 + (size_t)h * 2048;  // + hd*16*2048

  const int r0 = t >> 3, s0 = (t & 7) * 8;

  bf16x8 qf[2][2];
#pragma unroll
  for (int bt = 0; bt < 2; ++bt)
#pragma unroll
    for (int kk = 0; kk < 2; ++kk)
      qf[bt][kk] = *(const bf16x8*)(Qb + (size_t)(n0 + w * 32 + bt * 16 + li) * 64 + kk * 32 + q * 8);

  bf16x8 onef;
#pragma unroll
  for (int e = 0; e < 8; ++e) onef[e] = (bf16)1.0f;

  f32x4 acc[4][2];
#pragma unroll
  for (int i = 0; i < 4; ++i)
#pragma unroll
    for (int j = 0; j < 2; ++j) acc[i][j] = (f32x4){0.f, 0.f, 0.f, 0.f};
  f32x4 accl[2] = {(f32x4){0.f, 0.f, 0.f, 0.f}, (f32x4){0.f, 0.f, 0.f, 0.f}};

  bf16x8 kr0, vr0;
  kr0 = *(const bf16x8*)(Kb + (size_t)r0 * 64 + s0);
  vr0 = *(const bf16x8*)(Vb + (size_t)r0 * 32768 + s0);
  *(bf16x8*)&Ks[r0 * 72 + s0] = kr0;
  *(bf16x8*)&Vs[r0 * 72 + s0] = vr0;
  __syncthreads();

  for (int m0 = 0; m0 < 2048; m0 += 64) {
    const int mn = (m0 + 64 < 2048) ? m0 + 64 : m0;
    kr0 = *(const bf16x8*)(Kb + (size_t)(mn + r0) * 64 + s0);
    vr0 = *(const bf16x8*)(Vb + (size_t)r0 * 32768 + mn + s0);

    f32x4 sacc[4][2];
#pragma unroll
    for (int mt = 0; mt < 4; ++mt)
#pragma unroll
      for (int bt = 0; bt < 2; ++bt) sacc[mt][bt] = (f32x4){0.f, 0.f, 0.f, 0.f};
#pragma unroll
    for (int kk = 0; kk < 2; ++kk) {
#pragma unroll
      for (int mt = 0; mt < 4; ++mt) {
        bf16x8 af = *(const bf16x8*)&Ks[(mt * 16 + li) * 72 + kk * 32 + q * 8];
#pragma unroll
        for (int bt = 0; bt < 2; ++bt)
          sacc[mt][bt] = __builtin_amdgcn_mfma_f32_16x16x32_bf16(af, qf[bt][kk], sacc[mt][bt], 0, 0, 0);
      }
    }

    // exp2 and pack: pk32[bt][mt][hh] = {P[m=mt*16+q*4+2hh][n=li], P[m=..+2hh+1][n=li]}
    unsigned pk32[2][4][2];
#pragma unroll
    for (int mt = 0; mt < 4; ++mt)
#pragma unroll
      for (int bt = 0; bt < 2; ++bt) {
        bf16x4 pk;
#pragma unroll
        for (int r = 0; r < 4; ++r) pk[r] = (bf16)__builtin_amdgcn_exp2f(sacc[mt][bt][r]);
        uint2v pu = __builtin_bit_cast(uint2v, pk);
        pk32[bt][mt][0] = pu[0];
        pk32[bt][mt][1] = pu[1];
      }

#pragma unroll
    for (int kk = 0; kk < 2; ++kk) {
      bf16x8 pf[2];
#pragma unroll
      for (int bt = 0; bt < 2; ++bt) {
        uint4v du;
#pragma unroll
        for (int hh = 0; hh < 2; ++hh) {
          unsigned p0 = pk32[bt][2 * kk + 0][hh];
          unsigned p1 = pk32[bt][2 * kk + 1][hh];
          uint2v ab = __builtin_amdgcn_permlane32_swap(p0, p1, false, false);
          unsigned A = ab[0];   // [p0,p1,q0,q1] by 16-lane rows
          unsigned Bv = ab[1];  // [p2,p3,q2,q3]
          unsigned swzA = (unsigned)__builtin_amdgcn_ds_swizzle((int)A, 0x401F);
          unsigned swzB = (unsigned)__builtin_amdgcn_ds_swizzle((int)Bv, 0x401F);
          du[hh]     = oddrow ? swzB : A;   // X = [p0,p2,q0,q2]
          du[2 + hh] = oddrow ? Bv : swzA;  // Y = [p1,p3,q1,q3]
        }
        pf[bt] = __builtin_bit_cast(bf16x8, du);
        accl[bt] = __builtin_amdgcn_mfma_f32_16x16x32_bf16(onef, pf[bt], accl[bt], 0, 0, 0);
      }
#pragma unroll
      for (int hdt = 0; hdt < 4; ++hdt) {
        bf16x8 vf = *(const bf16x8*)&Vs[(hdt * 16 + li) * 72 + kk * 32 + q * 8];
#pragma unroll
        for (int bt = 0; bt < 2; ++bt)
          acc[hdt][bt] = __builtin_amdgcn_mfma_f32_16x16x32_bf16(vf, pf[bt], acc[hdt][bt], 0, 0, 0);
      }
    }

    __syncthreads();
    *(bf16x8*)&Ks[r0 * 72 + s0] = kr0;
    *(bf16x8*)&Vs[r0 * 72 + s0] = vr0;
    __syncthreads();
  }

  float inv[2] = {1.0f / accl[0][0], 1.0f / accl[1][0]};

  bf16* xb = xo + (size_t)b * 2048 * 1024 + (size_t)h * 64;
#pragma unroll
  for (int hdt = 0; hdt < 4; ++hdt)
#pragma unroll
    for (int bt = 0; bt < 2; ++bt) {
      int n = n0 + w * 32 + bt * 16 + li;
      bf16x4 o;
#pragma unroll
      for (int r = 0; r < 4; ++r) o[r] = (bf16)(acc[hdt][bt][r] * inv[bt]);
      *(bf16x4*)(xb + (size_t)n * 1024 + hdt * 16 + q * 4) = o;
    }
}

// ---------------- K5: weight prep. y=0..2: cvt Wq/Wk/Wv f32->bf16. y=3: permute Wm. ----
__global__ __launch_bounds__(256) void k_prepw(const float* __restrict__ Wq,
                                               const float* __restrict__ Wk,
                                               const float* __restrict__ Wv,
                                               const float* __restrict__ Wm,
                                               bf16* __restrict__ oq,
                                               bf16* __restrict__ ok,
                                               bf16* __restrict__ ov,
                                               bf16* __restrict__ om) {
  const int which = blockIdx.y;
  if (which < 3) {
    const float* s = (which == 0) ? Wq : ((which == 1) ? Wk : Wv);
    bf16* d = (which == 0) ? oq : ((which == 1) ? ok : ov);
    int idx = (blockIdx.x * 256 + threadIdx.x) * 4;
    f32x4 a = *(const f32x4*)(s + idx);
    bf16x4 o;
#pragma unroll
    for (int e = 0; e < 4; ++e) o[e] = (bf16)a[e];
    *(bf16x4*)(d + idx) = o;
  } else {
    // Wmp[o][h*64+hd] = Wm[o][hd*16+h]
#pragma unroll
    for (int p = 0; p < 4; ++p) {
      int idx = (blockIdx.x * 4 + p) * 256 + threadIdx.x;
      int o = idx >> 10, j = idx & 1023;
      int hd = j & 63, hh = j >> 6;
      om[idx] = (bf16)Wm[((size_t)o << 10) + (size_t)(hd * 16 + hh)];
    }
  }
}

extern "C" void kernel_launch(void* const* d_in, const int* in_sizes, int n_in,
                              void* d_out, int out_size, void* d_ws, size_t ws_size,
                              hipStream_t stream) {
  const float* query = (const float*)d_in[0];
  const float* key   = (const float*)d_in[1];
  const float* value = (const float*)d_in[2];
  const float* enc   = (const float*)d_in[3];
  const float* Wq = (const float*)d_in[4];  const float* bq = (const float*)d_in[5];
  const float* Wk = (const float*)d_in[6];  const float* bk = (const float*)d_in[7];
  const float* Wv = (const float*)d_in[8];  const float* bv = (const float*)d_in[9];
  const float* Wm = (const float*)d_in[10]; const float* bm = (const float*)d_in[11];

  // Workspace: 4 x 16 MB bf16 buffers + 4 x 2 MB bf16 weights = 72 MB (validated budget).
  // d_out (33.5 MB f32) doubles as scratch for v^T and vp until the final GEMM
  // overwrites every element of it.
  char* ws = (char*)d_ws;
  const size_t SZ = (size_t)4 * 2048 * 1024 * 2;  // 16 MB per [b][*][*] bf16 tensor
  const size_t WZ = (size_t)1024 * 1024 * 2;      // 2 MB per bf16 weight
  bf16* bufA = (bf16*)(ws + 0 * SZ);
  bf16* bufB = (bf16*)(ws + 1 * SZ);
  bf16* bufC = (bf16*)(ws + 2 * SZ);
  bf16* bufD = (bf16*)(ws + 3 * SZ);
  bf16* Wqb  = (bf16*)(ws + 4 * SZ + 0 * WZ);
  bf16* Wkb  = (bf16*)(ws + 4 * SZ + 1 * WZ);
  bf16* Wvb  = (bf16*)(ws + 4 * SZ + 2 * WZ);
  bf16* Wmp  = (bf16*)(ws + 4 * SZ + 3 * WZ);
  bf16* vt   = (bf16*)d_out;                          // v^T scratch (16 MB)
  bf16* vpd  = (bf16*)d_out + (size_t)4 * 2048 * 1024; // vp scratch (16 MB)

  dim3 blk(256);
  // weights
  k_prepw<<<dim3(1024, 4), blk, 0, stream>>>(Wq, Wk, Wv, Wm, Wqb, Wkb, Wvb, Wmp);
  // transposes: q->A, k->B, v->vt (d_out scratch)
  k_transpose3<<<dim3(32, 16, 12), blk, 0, stream>>>(query, key, value, bufA, bufB, vt);
  // fused QKV GEMM (8-phase 256x256, 512 threads; z=12, 384 blocks = 1/CU):
  // (Wq,A)->C, (Wk,B)->D, (Wv,vt)->vpd
  k_gemm3<<<dim3(8, 4, 12), dim3(512), 0, stream>>>(Wqb, Wkb, Wvb, bq, bk, bv,
                                                    bufA, bufB, vt, bufC, bufD, vpd);
  // fused rope (z=8): qp(C)->A (pre-scaled), kp(D)->B
  k_rope2<<<dim3(32, 16, 8), blk, 0, stream>>>(bufC, bufD, enc, bufA, bufB);
  // attn (512-thread blocks, 256 q-rows each): (A,B,vpd) -> C
  k_attn<<<dim3(8, 16, 4), dim3(512), 0, stream>>>(bufA, bufB, vpd, bufC);
  // out GEMM: C -> d_out (f32, overwrites scratch)
  k_gemm<float><<<dim3(16, 8, 4), blk, 0, stream>>>(Wmp, bufC, bm, (float*)d_out, 1024, 1024, 2048);
}

// Round 12
// 343.769 us; speedup vs baseline: 1.0703x; 1.0703x over previous
//
#include <hip/hip_runtime.h>
#include <hip/hip_bf16.h>

typedef __bf16 bf16;
typedef __bf16 bf16x8 __attribute__((ext_vector_type(8)));
typedef __bf16 bf16x4 __attribute__((ext_vector_type(4)));
typedef float f32x4 __attribute__((ext_vector_type(4)));
typedef unsigned int uint4v __attribute__((ext_vector_type(4)));
typedef unsigned int uint2v __attribute__((ext_vector_type(2)));

#define LOG2E 1.44269504088896340736f

typedef __attribute__((address_space(1))) const unsigned int guint;
typedef __attribute__((address_space(3))) unsigned int luint;

__device__ __forceinline__ void gload_lds16(const bf16* g, bf16* l) {
  // async global->LDS, 16B per lane; LDS dest = wave-uniform base + lane*16
  __builtin_amdgcn_global_load_lds((guint*)g, (luint*)l, 16, 0, 0);
}

// ------- K1: fused transpose x[b][i][n] (f32) -> xt[b][n][i] (bf16) for q,k,v ---------
__global__ __launch_bounds__(256) void k_transpose3(const float* __restrict__ q,
                                                    const float* __restrict__ k,
                                                    const float* __restrict__ v,
                                                    bf16* __restrict__ tq,
                                                    bf16* __restrict__ tk,
                                                    bf16* __restrict__ tv) {
  __shared__ bf16 T[64][72];
  const int t = threadIdx.x;
  const int n0 = blockIdx.x * 64;
  const int i0 = blockIdx.y * 64;
  const int z = blockIdx.z;
  const int b = z & 3, which = z >> 2;
  const float* src = (which == 0) ? q : ((which == 1) ? k : v);
  bf16* dst = (which == 0) ? tq : ((which == 1) ? tk : tv);
  const size_t srcb = (size_t)b * 1024 * 2048;
#pragma unroll
  for (int p = 0; p < 2; ++p) {
    int idx = p * 256 + t;
    int row = idx >> 3;   // i-local
    int seg = idx & 7;    // 8 n elems
    const float* sp = src + srcb + (size_t)(i0 + row) * 2048 + n0 + seg * 8;
    f32x4 a = *(const f32x4*)sp;
    f32x4 c = *(const f32x4*)(sp + 4);
    bf16x8 o;
#pragma unroll
    for (int e = 0; e < 4; ++e) { o[e] = (bf16)a[e]; o[4 + e] = (bf16)c[e]; }
    *(bf16x8*)&T[row][seg * 8] = o;
  }
  __syncthreads();
  const int j = t >> 2;       // n-local
  const int iseg = t & 3;     // 16 i elems
  bf16x8 o0, o1;
#pragma unroll
  for (int e = 0; e < 8; ++e) o0[e] = T[iseg * 16 + e][j];
#pragma unroll
  for (int e = 0; e < 8; ++e) o1[e] = T[iseg * 16 + 8 + e][j];
  bf16* dp = dst + (size_t)b * 2048 * 1024 + (size_t)(n0 + j) * 1024 + i0 + iseg * 16;
  *(bf16x8*)dp = o0;
  *(bf16x8*)(dp + 8) = o1;
}

// ------- K2a: fused QKV GEMM  C[b][o][n] = W(o,k)*Bt[b][n][k] + bias[o], z = which*4+b -
// Round-10 verified version: BK=64 + both-sides XOR swizzle, BM=256 x BN=128 with
// 512 threads / 8 waves (2x4 of 64x64 sub-tiles). LDS 48KB -> 3 blocks/CU.
// (Round-11's 8-phase 128KB-LDS port regressed: 1 block/CU + 384-block tail.)
__global__ __launch_bounds__(512, 4) void k_gemm3(const bf16* __restrict__ Wqb,
                                                  const bf16* __restrict__ Wkb,
                                                  const bf16* __restrict__ Wvb,
                                                  const float* __restrict__ bq,
                                                  const float* __restrict__ bk,
                                                  const float* __restrict__ bv,
                                                  const bf16* __restrict__ tq,
                                                  const bf16* __restrict__ tk,
                                                  const bf16* __restrict__ tv,
                                                  bf16* __restrict__ qp,
                                                  bf16* __restrict__ kp,
                                                  bf16* __restrict__ vp) {
  const int K = 1024, Nn = 2048;
  const int z = blockIdx.z;
  const int b = z & 3, which = z >> 2;
  const bf16* A = (which == 0) ? Wqb : ((which == 1) ? Wkb : Wvb);
  const bf16* Bt = (which == 0) ? tq : ((which == 1) ? tk : tv);
  const float* bias = (which == 0) ? bq : ((which == 1) ? bk : bv);
  bf16* C = (which == 0) ? qp : ((which == 1) ? kp : vp);

  __shared__ bf16 As[256 * 64];   // 32 KB
  __shared__ bf16 Bs[128 * 64];   // 16 KB
  const int t = threadIdx.x;
  const int w = t >> 6, l = t & 63, q = l >> 4, li = l & 15;
  const int o0 = blockIdx.y * 256, n0 = blockIdx.x * 128;
  const bf16* Ab = A + (size_t)o0 * K;
  const bf16* Bb = Bt + (size_t)b * Nn * K + (size_t)n0 * K;
  const int wr = (w >> 1) * 64, wc = (w & 1) * 64;   // wr 0..192, wc 0..64
  f32x4 acc[4][4];
#pragma unroll
  for (int i = 0; i < 4; ++i)
#pragma unroll
    for (int j = 0; j < 4; ++j) acc[i][j] = (f32x4){0.f, 0.f, 0.f, 0.f};

  // A: 2048 chunks of 16B per tile (4 passes x 512 threads); B: 1024 chunks (2 passes)
  int srow[4], sseg[4];
#pragma unroll
  for (int p = 0; p < 4; ++p) {
    int ci = p * 512 + t;
    srow[p] = ci >> 3;
    sseg[p] = ((ci & 7) ^ (srow[p] & 7)) * 8;  // pre-swizzled source column
  }
  const int swz = li & 7;  // read-side swizzle

  for (int k0 = 0; k0 < K; k0 += 64) {
    __syncthreads();
#pragma unroll
    for (int p = 0; p < 4; ++p)
      gload_lds16(Ab + (size_t)srow[p] * K + k0 + sseg[p], As + (size_t)(p * 512 + w * 64) * 8);
#pragma unroll
    for (int p = 0; p < 2; ++p)
      gload_lds16(Bb + (size_t)srow[p] * K + k0 + sseg[p], Bs + (size_t)(p * 512 + w * 64) * 8);
    __syncthreads();
#pragma unroll
    for (int kk = 0; kk < 2; ++kk) {
      const int cc = ((kk * 4 + q) ^ swz) * 8;
      bf16x8 af[4], bfr[4];
#pragma unroll
      for (int mt = 0; mt < 4; ++mt) af[mt] = *(const bf16x8*)&As[(wr + mt * 16 + li) * 64 + cc];
#pragma unroll
      for (int c = 0; c < 4; ++c) bfr[c] = *(const bf16x8*)&Bs[(wc + c * 16 + li) * 64 + cc];
#pragma unroll
      for (int mt = 0; mt < 4; ++mt)
#pragma unroll
        for (int c = 0; c < 4; ++c)
          acc[mt][c] = __builtin_amdgcn_mfma_f32_16x16x32_bf16(af[mt], bfr[c], acc[mt][c], 0, 0, 0);
    }
  }

  bf16* Cb = C + (size_t)b * K * Nn;
#pragma unroll
  for (int mt = 0; mt < 4; ++mt) {
#pragma unroll
    for (int r = 0; r < 4; ++r) {
      int o = o0 + wr + mt * 16 + q * 4 + r;
      float bvv = bias[o];
#pragma unroll
      for (int c = 0; c < 4; ++c) {
        int n = n0 + wc + c * 16 + li;
        Cb[(size_t)o * Nn + n] = (bf16)(acc[mt][c][r] + bvv);
      }
    }
  }
}

// ------- K2b: final projection GEMM, OT = float. Same 256x128/512-thread geometry as
// k_gemm3 (round-10 verified structure; parameter-only change from round-10's k_gemm). --
template <typename OT>
__global__ __launch_bounds__(512, 4) void k_gemm(const bf16* __restrict__ A,
                                                 const bf16* __restrict__ Bt,
                                                 const float* __restrict__ bias,
                                                 OT* __restrict__ C,
                                                 int M, int K, int Nn) {
  __shared__ bf16 As[256 * 64];
  __shared__ bf16 Bs[128 * 64];
  const int t = threadIdx.x;
  const int w = t >> 6, l = t & 63, q = l >> 4, li = l & 15;
  const int o0 = blockIdx.y * 256, n0 = blockIdx.x * 128;
  const int b = blockIdx.z;
  const bf16* Ab = A + (size_t)o0 * K;
  const bf16* Bb = Bt + (size_t)b * Nn * K + (size_t)n0 * K;
  const int wr = (w >> 1) * 64, wc = (w & 1) * 64;
  f32x4 acc[4][4];
#pragma unroll
  for (int i = 0; i < 4; ++i)
#pragma unroll
    for (int j = 0; j < 4; ++j) acc[i][j] = (f32x4){0.f, 0.f, 0.f, 0.f};

  int srow[4], sseg[4];
#pragma unroll
  for (int p = 0; p < 4; ++p) {
    int ci = p * 512 + t;
    srow[p] = ci >> 3;
    sseg[p] = ((ci & 7) ^ (srow[p] & 7)) * 8;
  }
  const int swz = li & 7;

  for (int k0 = 0; k0 < K; k0 += 64) {
    __syncthreads();
#pragma unroll
    for (int p = 0; p < 4; ++p)
      gload_lds16(Ab + (size_t)srow[p] * K + k0 + sseg[p], As + (size_t)(p * 512 + w * 64) * 8);
#pragma unroll
    for (int p = 0; p < 2; ++p)
      gload_lds16(Bb + (size_t)srow[p] * K + k0 + sseg[p], Bs + (size_t)(p * 512 + w * 64) * 8);
    __syncthreads();
#pragma unroll
    for (int kk = 0; kk < 2; ++kk) {
      const int cc = ((kk * 4 + q) ^ swz) * 8;
      bf16x8 af[4], bfr[4];
#pragma unroll
      for (int mt = 0; mt < 4; ++mt) af[mt] = *(const bf16x8*)&As[(wr + mt * 16 + li) * 64 + cc];
#pragma unroll
      for (int c = 0; c < 4; ++c) bfr[c] = *(const bf16x8*)&Bs[(wc + c * 16 + li) * 64 + cc];
#pragma unroll
      for (int mt = 0; mt < 4; ++mt)
#pragma unroll
        for (int c = 0; c < 4; ++c)
          acc[mt][c] = __builtin_amdgcn_mfma_f32_16x16x32_bf16(af[mt], bfr[c], acc[mt][c], 0, 0, 0);
    }
  }

  OT* Cb = C + (size_t)b * M * Nn;
#pragma unroll
  for (int mt = 0; mt < 4; ++mt) {
#pragma unroll
    for (int r = 0; r < 4; ++r) {
      int o = o0 + wr + mt * 16 + q * 4 + r;
      float bv = bias[o];
#pragma unroll
      for (int c = 0; c < 4; ++c) {
        int n = n0 + wc + c * 16 + li;
        Cb[(size_t)o * Nn + n] = (OT)(acc[mt][c][r] + bv);
      }
    }
  }
}

// ------- K3: fused RoPE q&k: p[b][hd*16+h][n] -> a[b][h][n][hd], z = which*4+b ---------
__global__ __launch_bounds__(256) void k_rope2(const bf16* __restrict__ qp,
                                               const bf16* __restrict__ kp,
                                               const float* __restrict__ enc,
                                               bf16* __restrict__ qa,
                                               bf16* __restrict__ ka) {
  __shared__ bf16 T[64][72];
  const int t = threadIdx.x;
  const int n0 = blockIdx.x * 64;
  const int h = blockIdx.y;
  const int z = blockIdx.z;
  const int b = z & 3, which = z >> 2;
  const bf16* src = which ? kp : qp;
  bf16* dst = which ? ka : qa;
  const float oscale = which ? 1.0f : 0.125f * LOG2E;
#pragma unroll
  for (int p = 0; p < 2; ++p) {
    int idx = p * 256 + t;
    int hd = idx >> 3;   // hd-local (row d = hd*16+h)
    int seg = idx & 7;
    *(bf16x8*)&T[hd][seg * 8] =
        *(const bf16x8*)(src + (size_t)(b * 1024 + hd * 16 + h) * 2048 + n0 + seg * 8);
  }
  __syncthreads();
  const int j = t >> 2;          // n-local
  const int hd0 = (t & 3) * 16;  // 16 hd elems
  const int n = n0 + j;
  const float* e0 = enc + (size_t)n * 64 + hd0;
  const float* e1 = enc + (size_t)2048 * 64 + (size_t)n * 64 + hd0;
  bf16x8 o0, o1;
#pragma unroll
  for (int i = 0; i < 8; ++i) {
    int e = 2 * i;
    float t0 = (float)T[hd0 + e][j];
    float t1 = (float)T[hd0 + e + 1][j];
    float f00 = e0[e], f01 = e0[e + 1];
    float f10 = e1[e], f11 = e1[e + 1];
    float r0 = (t0 * f00 - t1 * f10) * oscale;
    float r1 = (t1 * f01 + t0 * f11) * oscale;
    if (i < 4) { o0[e & 7] = (bf16)r0; o0[(e & 7) + 1] = (bf16)r1; }
    else       { o1[e & 7] = (bf16)r0; o1[(e & 7) + 1] = (bf16)r1; }
  }
  bf16* dp = dst + ((size_t)(b * 16 + h) * 2048 + n) * 64 + hd0;
  *(bf16x8*)dp = o0;
  *(bf16x8*)(dp + 8) = o1;
}

// ---------------- K4: flash attention v9 (round-9/10 verified version) ------------------
__global__ __launch_bounds__(512, 4) void k_attn(const bf16* __restrict__ qa,
                                                 const bf16* __restrict__ ka,
                                                 const bf16* __restrict__ vp,
                                                 bf16* __restrict__ xo) {
  __shared__ bf16 Ks[64 * 72];     // [m][hd]
  __shared__ bf16 Vs[64 * 72];     // [hd][m]
  const int t = threadIdx.x;
  const int w = t >> 6, l = t & 63, q = l >> 4, li = l & 15;
  const int n0 = blockIdx.x * 256, h = blockIdx.y, b = blockIdx.z;
  const bool oddrow = ((t >> 4) & 1) != 0;  // 16-lane row parity within the wave
  const bf16* Qb = qa + (size_t)(b * 16 + h) * 2048 * 64;
  const bf16* Kb = ka + (size_t)(b * 16 + h) * 2048 * 64;
  const bf16* Vb = vp + (size_t)b * 1024 * 2048 + (size_t)h * 2048;  // + hd*16*2048

  const int r0 = t >> 3, s0 = (t & 7) * 8;

  bf16x8 qf[2][2];
#pragma unroll
  for (int bt = 0; bt < 2; ++bt)
#pragma unroll
    for (int kk = 0; kk < 2; ++kk)
      qf[bt][kk] = *(const bf16x8*)(Qb + (size_t)(n0 + w * 32 + bt * 16 + li) * 64 + kk * 32 + q * 8);

  bf16x8 onef;
#pragma unroll
  for (int e = 0; e < 8; ++e) onef[e] = (bf16)1.0f;

  f32x4 acc[4][2];
#pragma unroll
  for (int i = 0; i < 4; ++i)
#pragma unroll
    for (int j = 0; j < 2; ++j) acc[i][j] = (f32x4){0.f, 0.f, 0.f, 0.f};
  f32x4 accl[2] = {(f32x4){0.f, 0.f, 0.f, 0.f}, (f32x4){0.f, 0.f, 0.f, 0.f}};

  bf16x8 kr0, vr0;
  kr0 = *(const bf16x8*)(Kb + (size_t)r0 * 64 + s0);
  vr0 = *(const bf16x8*)(Vb + (size_t)r0 * 32768 + s0);
  *(bf16x8*)&Ks[r0 * 72 + s0] = kr0;
  *(bf16x8*)&Vs[r0 * 72 + s0] = vr0;
  __syncthreads();

  for (int m0 = 0; m0 < 2048; m0 += 64) {
    const int mn = (m0 + 64 < 2048) ? m0 + 64 : m0;
    kr0 = *(const bf16x8*)(Kb + (size_t)(mn + r0) * 64 + s0);
    vr0 = *(const bf16x8*)(Vb + (size_t)r0 * 32768 + mn + s0);

    f32x4 sacc[4][2];
#pragma unroll
    for (int mt = 0; mt < 4; ++mt)
#pragma unroll
      for (int bt = 0; bt < 2; ++bt) sacc[mt][bt] = (f32x4){0.f, 0.f, 0.f, 0.f};
#pragma unroll
    for (int kk = 0; kk < 2; ++kk) {
#pragma unroll
      for (int mt = 0; mt < 4; ++mt) {
        bf16x8 af = *(const bf16x8*)&Ks[(mt * 16 + li) * 72 + kk * 32 + q * 8];
#pragma unroll
        for (int bt = 0; bt < 2; ++bt)
          sacc[mt][bt] = __builtin_amdgcn_mfma_f32_16x16x32_bf16(af, qf[bt][kk], sacc[mt][bt], 0, 0, 0);
      }
    }

    // exp2 and pack: pk32[bt][mt][hh] = {P[m=mt*16+q*4+2hh][n=li], P[m=..+2hh+1][n=li]}
    unsigned pk32[2][4][2];
#pragma unroll
    for (int mt = 0; mt < 4; ++mt)
#pragma unroll
      for (int bt = 0; bt < 2; ++bt) {
        bf16x4 pk;
#pragma unroll
        for (int r = 0; r < 4; ++r) pk[r] = (bf16)__builtin_amdgcn_exp2f(sacc[mt][bt][r]);
        uint2v pu = __builtin_bit_cast(uint2v, pk);
        pk32[bt][mt][0] = pu[0];
        pk32[bt][mt][1] = pu[1];
      }

#pragma unroll
    for (int kk = 0; kk < 2; ++kk) {
      bf16x8 pf[2];
#pragma unroll
      for (int bt = 0; bt < 2; ++bt) {
        uint4v du;
#pragma unroll
        for (int hh = 0; hh < 2; ++hh) {
          unsigned p0 = pk32[bt][2 * kk + 0][hh];
          unsigned p1 = pk32[bt][2 * kk + 1][hh];
          uint2v ab = __builtin_amdgcn_permlane32_swap(p0, p1, false, false);
          unsigned A = ab[0];   // [p0,p1,q0,q1] by 16-lane rows
          unsigned Bv = ab[1];  // [p2,p3,q2,q3]
          unsigned swzA = (unsigned)__builtin_amdgcn_ds_swizzle((int)A, 0x401F);
          unsigned swzB = (unsigned)__builtin_amdgcn_ds_swizzle((int)Bv, 0x401F);
          du[hh]     = oddrow ? swzB : A;   // X = [p0,p2,q0,q2]
          du[2 + hh] = oddrow ? Bv : swzA;  // Y = [p1,p3,q1,q3]
        }
        pf[bt] = __builtin_bit_cast(bf16x8, du);
        accl[bt] = __builtin_amdgcn_mfma_f32_16x16x32_bf16(onef, pf[bt], accl[bt], 0, 0, 0);
      }
#pragma unroll
      for (int hdt = 0; hdt < 4; ++hdt) {
        bf16x8 vf = *(const bf16x8*)&Vs[(hdt * 16 + li) * 72 + kk * 32 + q * 8];
#pragma unroll
        for (int bt = 0; bt < 2; ++bt)
          acc[hdt][bt] = __builtin_amdgcn_mfma_f32_16x16x32_bf16(vf, pf[bt], acc[hdt][bt], 0, 0, 0);
      }
    }

    __syncthreads();
    *(bf16x8*)&Ks[r0 * 72 + s0] = kr0;
    *(bf16x8*)&Vs[r0 * 72 + s0] = vr0;
    __syncthreads();
  }

  float inv[2] = {1.0f / accl[0][0], 1.0f / accl[1][0]};

  bf16* xb = xo + (size_t)b * 2048 * 1024 + (size_t)h * 64;
#pragma unroll
  for (int hdt = 0; hdt < 4; ++hdt)
#pragma unroll
    for (int bt = 0; bt < 2; ++bt) {
      int n = n0 + w * 32 + bt * 16 + li;
      bf16x4 o;
#pragma unroll
      for (int r = 0; r < 4; ++r) o[r] = (bf16)(acc[hdt][bt][r] * inv[bt]);
      *(bf16x4*)(xb + (size_t)n * 1024 + hdt * 16 + q * 4) = o;
    }
}

// ---------------- K5: weight prep. y=0..2: cvt Wq/Wk/Wv f32->bf16. y=3: permute Wm. ----
__global__ __launch_bounds__(256) void k_prepw(const float* __restrict__ Wq,
                                               const float* __restrict__ Wk,
                                               const float* __restrict__ Wv,
                                               const float* __restrict__ Wm,
                                               bf16* __restrict__ oq,
                                               bf16* __restrict__ ok,
                                               bf16* __restrict__ ov,
                                               bf16* __restrict__ om) {
  const int which = blockIdx.y;
  if (which < 3) {
    const float* s = (which == 0) ? Wq : ((which == 1) ? Wk : Wv);
    bf16* d = (which == 0) ? oq : ((which == 1) ? ok : ov);
    int idx = (blockIdx.x * 256 + threadIdx.x) * 4;
    f32x4 a = *(const f32x4*)(s + idx);
    bf16x4 o;
#pragma unroll
    for (int e = 0; e < 4; ++e) o[e] = (bf16)a[e];
    *(bf16x4*)(d + idx) = o;
  } else {
    // Wmp[o][h*64+hd] = Wm[o][hd*16+h]
#pragma unroll
    for (int p = 0; p < 4; ++p) {
      int idx = (blockIdx.x * 4 + p) * 256 + threadIdx.x;
      int o = idx >> 10, j = idx & 1023;
      int hd = j & 63, hh = j >> 6;
      om[idx] = (bf16)Wm[((size_t)o << 10) + (size_t)(hd * 16 + hh)];
    }
  }
}

extern "C" void kernel_launch(void* const* d_in, const int* in_sizes, int n_in,
                              void* d_out, int out_size, void* d_ws, size_t ws_size,
                              hipStream_t stream) {
  const float* query = (const float*)d_in[0];
  const float* key   = (const float*)d_in[1];
  const float* value = (const float*)d_in[2];
  const float* enc   = (const float*)d_in[3];
  const float* Wq = (const float*)d_in[4];  const float* bq = (const float*)d_in[5];
  const float* Wk = (const float*)d_in[6];  const float* bk = (const float*)d_in[7];
  const float* Wv = (const float*)d_in[8];  const float* bv = (const float*)d_in[9];
  const float* Wm = (const float*)d_in[10]; const float* bm = (const float*)d_in[11];

  // Workspace: 4 x 16 MB bf16 buffers + 4 x 2 MB bf16 weights = 72 MB (validated budget).
  // d_out (33.5 MB f32) doubles as scratch for v^T and vp until the final GEMM
  // overwrites every element of it.
  char* ws = (char*)d_ws;
  const size_t SZ = (size_t)4 * 2048 * 1024 * 2;  // 16 MB per [b][*][*] bf16 tensor
  const size_t WZ = (size_t)1024 * 1024 * 2;      // 2 MB per bf16 weight
  bf16* bufA = (bf16*)(ws + 0 * SZ);
  bf16* bufB = (bf16*)(ws + 1 * SZ);
  bf16* bufC = (bf16*)(ws + 2 * SZ);
  bf16* bufD = (bf16*)(ws + 3 * SZ);
  bf16* Wqb  = (bf16*)(ws + 4 * SZ + 0 * WZ);
  bf16* Wkb  = (bf16*)(ws + 4 * SZ + 1 * WZ);
  bf16* Wvb  = (bf16*)(ws + 4 * SZ + 2 * WZ);
  bf16* Wmp  = (bf16*)(ws + 4 * SZ + 3 * WZ);
  bf16* vt   = (bf16*)d_out;                          // v^T scratch (16 MB)
  bf16* vpd  = (bf16*)d_out + (size_t)4 * 2048 * 1024; // vp scratch (16 MB)

  dim3 blk(256);
  // weights
  k_prepw<<<dim3(1024, 4), blk, 0, stream>>>(Wq, Wk, Wv, Wm, Wqb, Wkb, Wvb, Wmp);
  // transposes: q->A, k->B, v->vt (d_out scratch)
  k_transpose3<<<dim3(32, 16, 12), blk, 0, stream>>>(query, key, value, bufA, bufB, vt);
  // fused QKV GEMM (512-thread, 256x128 tiles; z=12, 768 blocks = 3/CU):
  // (Wq,A)->C, (Wk,B)->D, (Wv,vt)->vpd
  k_gemm3<<<dim3(16, 4, 12), dim3(512), 0, stream>>>(Wqb, Wkb, Wvb, bq, bk, bv,
                                                     bufA, bufB, vt, bufC, bufD, vpd);
  // fused rope (z=8): qp(C)->A (pre-scaled), kp(D)->B
  k_rope2<<<dim3(32, 16, 8), blk, 0, stream>>>(bufC, bufD, enc, bufA, bufB);
  // attn (512-thread blocks, 256 q-rows each): (A,B,vpd) -> C
  k_attn<<<dim3(8, 16, 4), dim3(512), 0, stream>>>(bufA, bufB, vpd, bufC);
  // out GEMM (512-thread, 256x128 tiles; 256 blocks): C -> d_out (f32, overwrites scratch)
  k_gemm<float><<<dim3(16, 4, 4), dim3(512), 0, stream>>>(Wmp, bufC, bm, (float*)d_out,
                                                          1024, 1024, 2048);
}